// Round 5
// baseline (645.462 us; speedup 1.0000x reference)
//
#include <hip/hip_runtime.h>

typedef __attribute__((ext_vector_type(8))) short short8;
typedef __attribute__((ext_vector_type(4))) float f32x4;
typedef __attribute__((ext_vector_type(2))) float f32x2;
typedef __attribute__((ext_vector_type(2))) unsigned u32x2;
typedef unsigned short ushort_t;

#define WIMG 1216
#define HIMG 352

__device__ __forceinline__ float sigmoid_(float x){ return 1.f/(1.f+__expf(-x)); }
__device__ __forceinline__ float softplus_(float x){
  return fmaxf(x,0.f) + log1pf(__expf(-fabsf(x)));
}
__device__ __forceinline__ ushort_t f2b(float x){
  union { float f; unsigned u; } v; v.f = x;
  unsigned r = v.u + 0x7FFF + ((v.u >> 16) & 1);
  return (ushort_t)(r >> 16);
}
__device__ __forceinline__ unsigned pack_trunc(float a, float b){
  union { float f; unsigned u; } va, vb; va.f = a; vb.f = b;
  return (va.u >> 16) | (vb.u & 0xFFFF0000u);
}
// RTNE packed f32->bf16x2 in one instruction (compiler can't derive from bit-tricks)
__device__ __forceinline__ unsigned cvt_pk_bf16(float a, float b){
  unsigned r;
  asm("v_cvt_pk_bf16_f32 %0, %1, %2" : "=v"(r) : "v"(a), "v"(b));
  return r;
}
__device__ __forceinline__ f32x2 bf2x(unsigned u){
  union { unsigned uu[2]; f32x2 f; } v;
  v.uu[0] = u << 16; v.uu[1] = u & 0xFFFF0000u;
  return v.f;
}

// ---------- combined prep: transpose (blocks 0..8191) + weight pack (blocks 8192..9439) ----------
// pack layout blocks 0..37: [w_in ks0,ks1][i: wz*4, w0*4, w1*4]*3 ; block 38: w_out 16-col padded
__global__ __launch_bounds__(256)
void k_prep(const float* __restrict__ bev, ushort_t* __restrict__ vfh, int mode,
            const float* __restrict__ mw_in, const float* __restrict__ mwz,
            const float* __restrict__ mw0, const float* __restrict__ mw1,
            const float* __restrict__ mwo,
            const float* __restrict__ gw_in, const float* __restrict__ gwz,
            const float* __restrict__ gw0, const float* __restrict__ gw1,
            const float* __restrict__ gwo,
            ushort_t* __restrict__ pkM, ushort_t* __restrict__ pkG,
            float* __restrict__ out0){
  int bx = blockIdx.x;
  int tid = threadIdx.x;
  if (bx < 8192) {
    if (!mode) return;
    __shared__ float tile[64][65];
    int y0 = (bx & 1) * 64;
    int c0 = ((bx >> 1) & 1) * 64;
    int zx = bx >> 2;
    const float* s = bev + (size_t)(zx >> 7)*2097152 + (size_t)c0*16384 + (size_t)(zx & 127)*128 + y0;
    int r0 = tid >> 4, f4 = tid & 15;
    #pragma unroll
    for (int it = 0; it < 4; ++it) {
      int c = it*16 + r0;
      f32x4 v = __builtin_nontemporal_load((const f32x4*)(s + (size_t)c*16384 + f4*4));
      tile[c][f4*4+0]=v.x; tile[c][f4*4+1]=v.y; tile[c][f4*4+2]=v.z; tile[c][f4*4+3]=v.w;
    }
    __syncthreads();
    ushort_t* d = vfh + ((size_t)zx*128 + y0)*128 + c0;
    #pragma unroll
    for (int it = 0; it < 4; ++it) {
      int y = it*16 + r0;
      u32x2 o;
      o.x = pack_trunc(tile[f4*4+0][y], tile[f4*4+1][y]);
      o.y = pack_trunc(tile[f4*4+2][y], tile[f4*4+3][y]);
      __builtin_nontemporal_store(o, (u32x2*)(d + (size_t)y*128 + f4*4));
    }
    return;
  }
  int pb = bx - 8192;                 // 0..1247 ; 624 per net
  if (pb == 0 && tid == 0) out0[0] = 0.f;
  int net = pb >= 624;                // 0 = M, 1 = G
  const float* w_in = net ? gw_in : mw_in;
  const float* wz   = net ? gwz   : mwz;
  const float* w0   = net ? gw0   : mw0;
  const float* w1   = net ? gw1   : mw1;
  const float* wo   = net ? gwo   : mwo;
  int outd = net ? 2 : 4;
  ushort_t* pk = net ? pkG : pkM;
  int id = (pb - (net ? 624 : 0))*256 + tid;
  if (id >= 39*4096) return;
  int blk = id >> 12;
  int e = id & 4095;
  float val = 0.f;
  if (blk < 38) {
    int nt = e >> 9, lane = (e >> 3) & 63, j = e & 7;
    int kloc = (lane >> 4)*8 + j;
    int n = nt*16 + (lane & 15);
    if (blk < 2) {
      int k = blk*32 + kloc;
      val = (k < 42) ? w_in[k*128 + n] : 0.f;
    } else {
      int g = blk - 2;
      int i = g / 12, r = g % 12, m = r >> 2, ks = r & 3;
      int k = ks*32 + kloc;
      const float* src = (m==0 ? wz : (m==1 ? w0 : w1)) + i*16384;
      val = src[k*128 + n];
    }
  } else if (e < 2048) {
    int ks = e >> 9, lane = (e >> 3) & 63, j = e & 7;
    int k = ks*32 + (lane >> 4)*8 + j;
    int n = lane & 15;
    val = (n < outd) ? wo[k*outd + n] : 0.f;
  }
  pk[id] = f2b(val);
}

// ---------- fragment GEMM, 8-wave partition: wave owns 32 out-channels (cg) x 32 points (pg) ----
// weights (A) loaded inline (L1/L2-resident); acts (B) in LDS fragment order:
// (ks*4 + pg*2 + nt)*512 + lane*8.
// SWZ: 16B-unit XOR swizzle (idx = l ^ (l>>3) ^ ks on low 3 bits) matching gather writes.
template<int KS, bool SWZ>
__device__ __forceinline__ void gemm_frag(const ushort_t* lds,
                                          const ushort_t* __restrict__ pkW,
                                          f32x4 acc[2][2], int cg, int pg, int lane)
{
  short8 w[KS][2];
  #pragma unroll
  for (int ks = 0; ks < KS; ++ks)
    #pragma unroll
    for (int ct = 0; ct < 2; ++ct)
      w[ks][ct] = *(const short8*)(pkW + (size_t)((ks*8 + cg*2 + ct)*64 + lane)*8);
  #pragma unroll
  for (int ks = 0; ks < KS; ++ks) {
    int idx = SWZ ? ((lane & ~7) | ((lane ^ (lane >> 3) ^ ks) & 7)) : lane;
    short8 b[2];
    #pragma unroll
    for (int nt = 0; nt < 2; ++nt)
      b[nt] = *(const short8*)(lds + (ks*4 + pg*2 + nt)*512 + idx*8);
    __builtin_amdgcn_s_setprio(1);
    #pragma unroll
    for (int ct = 0; ct < 2; ++ct)
      #pragma unroll
      for (int nt = 0; nt < 2; ++nt)
        acc[ct][nt] = __builtin_amdgcn_mfma_f32_16x16x32_bf16(w[ks][ct], b[nt], acc[ct][nt], 0,0,0);
    __builtin_amdgcn_s_setprio(0);
  }
}

// D: channel c = cg*32 + ct*16 + quad*4 + r ; point p = (pg*2+nt)*16 + l15
// fragment-order store: frag = cg*4 + pg*2 + nt ; lane' = (ct*2 + (quad>>1))*16 + l15 ; j = (quad&1)*4
__device__ __forceinline__ void store_reluF(ushort_t* buf, const f32x4 acc[2][2],
                                            int cg, int pg, int lane){
  int l15 = lane & 15, quad = lane >> 4;
  int j = (quad & 1)*4;
  #pragma unroll
  for (int ct = 0; ct < 2; ++ct) {
    int lp = (ct*2 + (quad >> 1))*16 + l15;
    #pragma unroll
    for (int nt = 0; nt < 2; ++nt) {
      uint2 o;
      o.x = cvt_pk_bf16(fmaxf(acc[ct][nt][0],0.f), fmaxf(acc[ct][nt][1],0.f));
      o.y = cvt_pk_bf16(fmaxf(acc[ct][nt][2],0.f), fmaxf(acc[ct][nt][3],0.f));
      *(uint2*)(buf + (cg*4 + pg*2 + nt)*512 + lp*8 + j) = o;
    }
  }
}

// ---------- fused: OUTD=2 gauss (rayinit + MLP + sort), OUTD=4 main (MLP) ----------
// 512 threads = 8 waves/block; LDS 32 KB static -> 4 blocks/CU = 32 waves/CU (slot max).
// Aux setup arrays overlay Wb (dead before PE writes Wb); sMean/sStd overlay zf at +12 KB.
template<int OUTD>
__global__ __launch_bounds__(512, 8)
void k_fused(const ushort_t* __restrict__ vfh, const float* __restrict__ vf0, int mode,
             const float* __restrict__ camK, const int* __restrict__ pix,
             const float* __restrict__ noise,
             float* __restrict__ unit, float* __restrict__ viewdir,
             const float* __restrict__ Tsi, float* __restrict__ dsort,
             const ushort_t* __restrict__ pk,
             const float* __restrict__ b_in, const float* __restrict__ bzv,
             const float* __restrict__ b0v, const float* __restrict__ b1v,
             const float* __restrict__ b_out,
             float* __restrict__ means, float* __restrict__ stds, float* __restrict__ outbuf)
{
  __shared__ __align__(16) ushort_t smem[16384];   // 32768 B exactly
  ushort_t* zf = smem;            // 16 KB
  ushort_t* Wb = smem + 8192;     // 16 KB
  // aux overlay inside Wb (bytes 0..3456) — dead before PE writes Wb
  float* auxf = (float*)Wb;
  int*   sOff = (int*)auxf;                         // [64]
  float (*sW)[8] = (float(*)[8])(auxf + 64);        // [64][8]
  float* sPx = auxf + 576;                          // [64]
  float* sPy = auxf + 640;
  float* sPz = auxf + 704;
  float* sUx = auxf + 768; float* sUy = auxf + 784; float* sUz = auxf + 800;
  float* sVx = auxf + 816; float* sVy = auxf + 832; float* sVz = auxf + 848;
  // sMean/sStd overlay zf at +12 KB (OUTD==2 only; sort's fbuf uses zf[0..4 KB))
  float* zff = (float*)zf;
  float* sMean = zff + 3072;                        // [64]
  float* sStd  = zff + 3136;                        // [64]

  int tid = threadIdx.x;
  int wv = tid >> 6, lane = tid & 63;
  int cg = wv & 3, pg = wv >> 2;
  int qbase = blockIdx.x * 64;

  if constexpr (OUTD == 2) {
    if (tid < 16) {
      int gray = (qbase >> 2) + tid;
      float a=camK[0],b=camK[1],c=camK[2],d=camK[3],e=camK[4],f=camK[5],g=camK[6],h=camK[7],i=camK[8];
      float c00 = e*i-f*h, c01 = c*h-b*i, c02 = b*f-c*e;
      float c10 = f*g-d*i, c11 = a*i-c*g, c12 = c*d-a*f;
      float c20 = d*h-e*g, c21 = b*g-a*h, c22 = a*e-b*d;
      float det = a*c00 + b*c10 + c*c20;
      float id = 1.f/det;
      float u = (float)pix[2*gray], v = (float)pix[2*gray+1];
      float dx = (c00*u + c01*v + c02)*id;
      float dy = (c10*u + c11*v + c12)*id;
      float dz = (c20*u + c21*v + c22)*id;
      float n = sqrtf(dx*dx+dy*dy+dz*dz);
      dx/=n; dy/=n; dz/=n;
      sUx[tid]=dx; sUy[tid]=dy; sUz[tid]=dz;
      unit[3*gray]=dx; unit[3*gray+1]=dy; unit[3*gray+2]=dz;
      float vx = Tsi[0]*dx + Tsi[1]*dy + Tsi[2]*dz;
      float vy = Tsi[4]*dx + Tsi[5]*dy + Tsi[6]*dz;
      float vz = Tsi[8]*dx + Tsi[9]*dy + Tsi[10]*dz;
      sVx[tid]=vx; sVy[tid]=vy; sVz[tid]=vz;
      viewdir[3*gray]=vx; viewdir[3*gray+1]=vy; viewdir[3*gray+2]=vz;
    }
  } else {
    if (tid == 0) {
      int ray = blockIdx.x;
      sUx[0]=unit[3*ray]; sUy[0]=unit[3*ray+1]; sUz[0]=unit[3*ray+2];
      sVx[0]=viewdir[3*ray]; sVy[0]=viewdir[3*ray+1]; sVz[0]=viewdir[3*ray+2];
    }
  }
  __syncthreads();

  if (tid < 64) {
    float t, ux, uy, uz;
    if constexpr (OUTD == 2) {
      t = ((float)(tid & 3) + 0.5f) * 25.f;
      int lr = tid >> 2;
      ux = sUx[lr]; uy = sUy[lr]; uz = sUz[lr];
    } else {
      t = dsort[qbase + tid];
      ux = sUx[0]; uy = sUy[0]; uz = sUz[0];
    }
    float wx=ux*t, wy=uy*t, wz=uz*t;
    float px = Tsi[0]*wx + Tsi[1]*wy + Tsi[2]*wz + Tsi[3];
    float py = Tsi[4]*wx + Tsi[5]*wy + Tsi[6]*wz + Tsi[7];
    float pz = Tsi[8]*wx + Tsi[9]*wy + Tsi[10]*wz + Tsi[11];
    sPx[tid]=px; sPy[tid]=py; sPz[tid]=pz;
    float gx = (px + 25.6f)*2.5f;
    float gy = (py + 25.6f)*2.5f;
    float gz = (pz + 2.0f)*2.5f;
    bool inb = (gx>=0.f)&&(gx<=127.f)&&(gy>=0.f)&&(gy<=127.f)&&(gz>=0.f)&&(gz<=15.f);
    gx = fminf(fmaxf(gx,0.f),127.f);
    gy = fminf(fmaxf(gy,0.f),127.f);
    gz = fminf(fmaxf(gz,0.f),15.f);
    int x0 = min(max((int)floorf(gx),0),126);
    int y0 = min(max((int)floorf(gy),0),126);
    int z0 = min(max((int)floorf(gz),0),14);
    float fx = gx-(float)x0, fy = gy-(float)y0, fz = gz-(float)z0;
    float sc = inb ? 1.f : 0.f;
    float ax0 = 1.f-fx, ay0 = 1.f-fy;
    float az0 = (1.f-fz)*sc, az1 = fz*sc;
    float q00 = ax0*ay0, q01 = ax0*fy, q10 = fx*ay0, q11 = fx*fy;
    sW[tid][0] = az0*q00; sW[tid][1] = az0*q01; sW[tid][2] = az0*q10; sW[tid][3] = az0*q11;
    sW[tid][4] = az1*q00; sW[tid][5] = az1*q01; sW[tid][6] = az1*q10; sW[tid][7] = az1*q11;
    sOff[tid] = mode ? (((z0*128 + x0)*128 + y0)*128)
                     : (z0*2097152 + x0*128 + y0);
  }
  __syncthreads();

  // trilinear gather -> zf in fragment order (XOR-swizzled 16B units), packed f32x2 math
  for (int it = 0; it < 2; ++it) {
    int lin = it*512 + tid;
    int p = lin >> 4, cb = lin & 15;
    float4 wA = *(const float4*)&sW[p][0];
    float4 wB = *(const float4*)&sW[p][4];
    f32x2 r01={0.f,0.f}, r23={0.f,0.f}, r45={0.f,0.f}, r67={0.f,0.f};
    if (mode) {
      const ushort_t* b = vfh + sOff[p] + cb*8;
      uint4 v;
      #define ACC8(PTR, W) \
        v = *(const uint4*)(PTR); \
        r01 += (W)*bf2x(v.x); r23 += (W)*bf2x(v.y); \
        r45 += (W)*bf2x(v.z); r67 += (W)*bf2x(v.w);
      ACC8(b,                     wA.x)
      ACC8(b + 128,               wA.y)
      ACC8(b + 16384,             wA.z)
      ACC8(b + 16384 + 128,       wA.w)
      ACC8(b + 2097152,           wB.x)
      ACC8(b + 2097152 + 128,     wB.y)
      ACC8(b + 2097152 + 16384,   wB.z)
      ACC8(b + 2097152 + 16512,   wB.w)
      #undef ACC8
    } else {
      const float* bsrc = vf0 + sOff[p];
      float rr[8];
      #pragma unroll
      for (int k = 0; k < 8; ++k) {
        const float* bc = bsrc + (size_t)(cb*8 + k)*16384;
        rr[k] = wA.x*bc[0] + wA.y*bc[1] + wA.z*bc[128] + wA.w*bc[129]
              + wB.x*bc[2097152] + wB.y*bc[2097153] + wB.z*bc[2097280] + wB.w*bc[2097281];
      }
      r01 = (f32x2){rr[0],rr[1]}; r23 = (f32x2){rr[2],rr[3]};
      r45 = (f32x2){rr[4],rr[5]}; r67 = (f32x2){rr[6],rr[7]};
    }
    uint4 o;
    o.x = cvt_pk_bf16(r01.x, r01.y); o.y = cvt_pk_bf16(r23.x, r23.y);
    o.z = cvt_pk_bf16(r45.x, r45.y); o.w = cvt_pk_bf16(r67.x, r67.y);
    int T = (cb >> 2)*4 + (p >> 4);
    int lanep = (cb & 3)*16 + (p & 15);
    // write-side swizzle must match gemm_frag's read swizzle: ks = cb>>2 = T>>2
    int lsw = (lanep & ~7) | ((lanep ^ (lanep >> 3) ^ (cb >> 2)) & 7);
    *(uint4*)(zf + T*512 + lsw*8) = o;
  }

  // hoist this thread's PE coords out of the aux overlay BEFORE Wb is overwritten
  int pp = lane;
  float ppx = sPx[pp], ppy = sPy[pp], ppz = sPz[pp];
  int plr = (OUTD == 2) ? (pp >> 2) : 0;
  float pvx = sVx[plr], pvy = sVy[plr], pvz = sVz[plr];
  __syncthreads();   // all aux reads (gather + coords) complete; Wb may now be written

  // PE inputs -> Wb in fragment order (k=0..63, dims 42..63 zero)
  // one thread per (point=lane, d-group-of-8 = wave): one packed b128 write each
  {
    int p = pp, g = wv;
    float vals[8];
    #pragma unroll
    for (int j = 0; j < 8; ++j) {
      int d = g*8 + j;
      float val = 0.f;
      if (d < 3)      val = (d==0)?ppx:((d==1)?ppy:ppz);
      else if (d < 39) {
        int s = d - 3; bool isSin = (s < 18); if (!isSin) s -= 18;
        int axis = s/6, fi = s%6;
        float base = (axis==0)?ppx:((axis==1)?ppy:ppz);
        float arg = base * (float)(1 << fi);
        val = isSin ? __sinf(arg) : __cosf(arg);
      } else if (d < 42) {
        val = (d==39)?pvx:((d==40)?pvy:pvz);
      }
      vals[j] = val;
    }
    uint4 o;
    o.x = cvt_pk_bf16(vals[0], vals[1]);
    o.y = cvt_pk_bf16(vals[2], vals[3]);
    o.z = cvt_pk_bf16(vals[4], vals[5]);
    o.w = cvt_pk_bf16(vals[6], vals[7]);
    *(uint4*)(Wb + (g>>2)*2048 + (p>>4)*512 + ((g&3)*16 + (p&15))*8) = o;
  }
  __syncthreads();

  int l15 = lane & 15, quad = lane >> 4;
  int cbase = cg*32 + quad*4;       // channel base for ct=0 (ct=1 adds 16)

  f32x4 h[2][2];
  #pragma unroll
  for (int ct = 0; ct < 2; ++ct) {
    f32x4 bi = *(const f32x4*)(b_in + cbase + ct*16);
    #pragma unroll
    for (int nt = 0; nt < 2; ++nt) h[ct][nt] = bi;
  }
  gemm_frag<2,false>(Wb, pk, h, cg, pg, lane);

  const ushort_t* pkl = pk + 2*4096;
  #pragma unroll 1
  for (int i3 = 0; i3 < 3; ++i3) {
    gemm_frag<4,true>(zf, pkl + (size_t)(i3*12)*4096, h, cg, pg, lane);
    #pragma unroll
    for (int ct = 0; ct < 2; ++ct) {
      f32x4 bz = *(const f32x4*)(bzv + i3*128 + cbase + ct*16);
      #pragma unroll
      for (int nt = 0; nt < 2; ++nt) h[ct][nt] += bz;
    }
    __syncthreads();
    store_reluF(Wb, h, cg, pg, lane);
    __syncthreads();
    f32x4 net[2][2];
    #pragma unroll
    for (int ct = 0; ct < 2; ++ct) {
      f32x4 c0b = *(const f32x4*)(b0v + i3*128 + cbase + ct*16);
      #pragma unroll
      for (int nt = 0; nt < 2; ++nt) net[ct][nt] = c0b;
    }
    gemm_frag<4,false>(Wb, pkl + (size_t)(i3*12+4)*4096, net, cg, pg, lane);
    __syncthreads();
    store_reluF(Wb, net, cg, pg, lane);
    __syncthreads();
    gemm_frag<4,false>(Wb, pkl + (size_t)(i3*12+8)*4096, h, cg, pg, lane);
    #pragma unroll
    for (int ct = 0; ct < 2; ++ct) {
      f32x4 o1b = *(const f32x4*)(b1v + i3*128 + cbase + ct*16);
      #pragma unroll
      for (int nt = 0; nt < 2; ++nt) h[ct][nt] += o1b;
    }
  }
  __syncthreads();
  store_reluF(Wb, h, cg, pg, lane);
  __syncthreads();

  // epilogue: one 16x16 MFMA per wave for waves 0..3; wave owns points wv*16..+15
  if (wv < 4) {
    const ushort_t* pkw = pk + 38*4096;
    f32x4 oa = (f32x4){0.f,0.f,0.f,0.f};
    #pragma unroll
    for (int ks = 0; ks < 4; ++ks) {
      short8 w = *(const short8*)(pkw + (size_t)(ks*64 + lane)*8);
      short8 b = *(const short8*)(Wb + (ks*4 + wv)*512 + lane*8);
      oa = __builtin_amdgcn_mfma_f32_16x16x32_bf16(w, b, oa, 0,0,0);
    }
    if (quad == 0) {
      int lq = wv*16 + l15;
      int q = qbase + lq;
      if constexpr (OUTD == 4) {
        float4 o = { oa[0] + b_out[0], oa[1] + b_out[1], oa[2] + b_out[2], oa[3] + b_out[3] };
        *(float4*)(outbuf + (size_t)q*4) = o;
      } else {
        int g = q & 3;
        float m = fminf(fmaxf(((float)g + 0.5f)*25.f + oa[0] + b_out[0], 0.5f), 100.f);
        float sd = 2.5f*sigmoid_(oa[1] + b_out[1]) + 0.1f;
        means[q] = m; stds[q] = sd;
        sMean[lq] = m; sStd[lq] = sd;
      }
    }
  }

  // gauss: fused depth-set build + rank-sort (16 rays/block; threads 0..255 active)
  if constexpr (OUTD == 2) {
    __syncthreads();
    float* fbuf = zff;                 // zf[0..4 KB) — sMean/sStd live at +12 KB
    int lr = tid >> 4;
    int sbase = (tid & 15) * 4;
    float vals[4];
    if (tid < 256) {
      #pragma unroll
      for (int s = 0; s < 4; ++s) {
        int slot = sbase + s;
        float val;
        if (slot < 32) val = 0.5f + (float)slot * (99.5f/31.f);
        else {
          int idx = slot - 32, g = idx >> 3, sx = idx & 7;
          int lq = lr*4 + g;
          float mu = sMean[lq], sd = sStd[lq];
          val = fminf(fmaxf(mu + sd*noise[(size_t)(qbase + lq)*8 + sx], 0.5f), 100.f);
        }
        fbuf[lr*64 + slot] = val;
        vals[s] = val;
      }
    }
    __syncthreads();
    if (tid < 256) {
      int rk[4] = {0,0,0,0};
      for (int k = 0; k < 64; ++k) {
        float o = fbuf[lr*64 + k];
        #pragma unroll
        for (int s = 0; s < 4; ++s)
          rk[s] += (o < vals[s]) || (o == vals[s] && k < sbase + s);
      }
      int gray = (qbase >> 2) + lr;
      #pragma unroll
      for (int s = 0; s < 4; ++s)
        dsort[(size_t)gray*64 + rk[s]] = vals[s];
    }
  }
}

// ---------- render + losses: one wave per ray, atomic total ----------
__device__ __forceinline__ void bilin3(const float* __restrict__ img, float u, float v, float* out){
  u = fminf(fmaxf(u, 0.f), (float)(WIMG-1));
  v = fminf(fmaxf(v, 0.f), (float)(HIMG-1));
  int u0 = min(max((int)floorf(u),0), WIMG-2);
  int v0 = min(max((int)floorf(v),0), HIMG-2);
  float fu = u - (float)u0, fv = v - (float)v0;
  float w00=(1.f-fv)*(1.f-fu), w01=(1.f-fv)*fu, w10=fv*(1.f-fu), w11=fv*fu;
  #pragma unroll
  for (int c = 0; c < 3; ++c) {
    const float* b = img + (size_t)c*(HIMG*WIMG) + (size_t)v0*WIMG + u0;
    out[c] = w00*b[0] + w01*b[1] + w10*b[WIMG] + w11*b[WIMG+1];
  }
}

__global__ void k_render(const float* __restrict__ outbuf, const float* __restrict__ dsort,
                         const float* __restrict__ means, const float* __restrict__ stds,
                         const float* __restrict__ unit,
                         const float* __restrict__ img_src, const float* __restrict__ img_tgt,
                         const int* __restrict__ pix, const float* __restrict__ camK,
                         const float* __restrict__ Tst, float* __restrict__ loss_out, int R){
  __shared__ float accw[4];
  int gid = blockIdx.x*blockDim.x + threadIdx.x;
  int r = gid >> 6, lane = gid & 63;
  float d = dsort[(size_t)r*64 + lane];
  float dn = __shfl_down(d, 1);
  float delta = (lane < 63) ? (dn - d) : 1e10f;
  float4 o = *(const float4*)(outbuf + (size_t)r*256 + lane*4);
  float sig = softplus_(o.x);
  float alpha = 1.f - __expf(-sig*delta);
  float om = 1.f - alpha + 1e-10f;
  float prod = om;
  #pragma unroll
  for (int off = 1; off < 64; off <<= 1) {
    float v = __shfl_up(prod, off);
    if (lane >= off) prod *= v;
  }
  float texc = __shfl_up(prod, 1);
  if (lane == 0) texc = 1.f;
  float w = alpha * texc;
  float m0=means[r*4],m1=means[r*4+1],m2=means[r*4+2],m3=means[r*4+3];
  float s0=stds[r*4], s1=stds[r*4+1], s2=stds[r*4+2], s3=stds[r*4+3];
  float t0=(d-m0)/s0, t1=(d-m1)/s1, t2=(d-m2)/s2, t3=(d-m3)/s3;
  float pm = 0.25f*0.3989422804014327f*(__expf(-0.5f*t0*t0)/s0 + __expf(-0.5f*t1*t1)/s1
                                      + __expf(-0.5f*t2*t2)/s2 + __expf(-0.5f*t3*t3)/s3);
  float kl  = w * (-__logf(pm + 1e-6f));
  float dep = w * d;
  float c0 = w * sigmoid_(o.y);
  float c1 = w * sigmoid_(o.z);
  float c2 = w * sigmoid_(o.w);
  #pragma unroll
  for (int off = 32; off; off >>= 1) {
    dep += __shfl_xor(dep, off);
    c0  += __shfl_xor(c0, off);
    c1  += __shfl_xor(c1, off);
    c2  += __shfl_xor(c2, off);
    kl  += __shfl_xor(kl, off);
  }
  if (lane == 0) {
    float ld = fminf(fminf(fabsf(m0-dep),fabsf(m1-dep)), fminf(fabsf(m2-dep),fabsf(m3-dep)));
    float src[3], tgt[3];
    float u = (float)pix[2*r], v = (float)pix[2*r+1];
    bilin3(img_src, u, v, src);
    float ux=unit[3*r],uy=unit[3*r+1],uz=unit[3*r+2];
    float pcx=ux*dep, pcy=uy*dep, pcz=uz*dep;
    float ptx = Tst[0]*pcx + Tst[1]*pcy + Tst[2]*pcz + Tst[3];
    float pty = Tst[4]*pcx + Tst[5]*pcy + Tst[6]*pcz + Tst[7];
    float ptz = Tst[8]*pcx + Tst[9]*pcy + Tst[10]*pcz + Tst[11];
    float prx = camK[0]*ptx + camK[1]*pty + camK[2]*ptz;
    float pry = camK[3]*ptx + camK[4]*pty + camK[5]*ptz;
    float prz = camK[6]*ptx + camK[7]*pty + camK[8]*ptz;
    prz = fmaxf(prz, 0.001f);
    bilin3(img_tgt, prx/prz, pry/prz, tgt);
    float lrepr = fabsf(src[0]-tgt[0])+fabsf(src[1]-tgt[1])+fabsf(src[2]-tgt[2]);
    float lcol  = fabsf(src[0]-c0)+fabsf(src[1]-c1)+fabsf(src[2]-c2);
    float invR = 1.f/(float)R;
    accw[threadIdx.x >> 6] = (lrepr + lcol) * (invR/3.f) + kl*invR + 0.01f*ld*invR;
  }
  __syncthreads();
  if (threadIdx.x == 0)
    atomicAdd(loss_out, accw[0]+accw[1]+accw[2]+accw[3]);
}

extern "C" void kernel_launch(void* const* d_in, const int* in_sizes, int n_in,
                              void* d_out, int out_size, void* d_ws, size_t ws_size,
                              hipStream_t stream)
{
  const float* bev   = (const float*)d_in[0];
  const float* camK  = (const float*)d_in[1];
  const float* img_s = (const float*)d_in[2];
  const float* img_t = (const float*)d_in[3];
  const float* Tsi   = (const float*)d_in[4];
  const float* Tst   = (const float*)d_in[5];
  const float* noise = (const float*)d_in[6];
  const int*   pix   = (const int*)d_in[7];
  const float* m_w_in=(const float*)d_in[8];  const float* m_b_in=(const float*)d_in[9];
  const float* m_wz  =(const float*)d_in[10]; const float* m_bz  =(const float*)d_in[11];
  const float* m_w0  =(const float*)d_in[12]; const float* m_b0  =(const float*)d_in[13];
  const float* m_w1  =(const float*)d_in[14]; const float* m_b1  =(const float*)d_in[15];
  const float* m_wo  =(const float*)d_in[16]; const float* m_bo  =(const float*)d_in[17];
  const float* g_w_in=(const float*)d_in[18]; const float* g_b_in=(const float*)d_in[19];
  const float* g_wz  =(const float*)d_in[20]; const float* g_bz  =(const float*)d_in[21];
  const float* g_w0  =(const float*)d_in[22]; const float* g_b0  =(const float*)d_in[23];
  const float* g_w1  =(const float*)d_in[24]; const float* g_b1  =(const float*)d_in[25];
  const float* g_wo  =(const float*)d_in[26]; const float* g_bo  =(const float*)d_in[27];

  int R = in_sizes[7] / 2;
  float* ws = (float*)d_ws;
  size_t off = 0;
  float* unitb = ws + off; off += (size_t)R*3;
  float* vdirb = ws + off; off += (size_t)R*3;
  float* means = ws + off; off += (size_t)R*4;
  float* stds  = ws + off; off += (size_t)R*4;
  float* dsort = ws + off; off += (size_t)R*64;
  float* outbf = ws + off; off += (size_t)R*256;
  ushort_t* pkM = (ushort_t*)(ws + off);
  ushort_t* pkG = pkM + 39*4096;
  off += 39*4096 + 64;
  off = (off + 63) & ~(size_t)63;
  ushort_t* vfh = (ushort_t*)(ws + off);
  size_t need = off*4ull + (size_t)16*128*128*128*2ull;
  int mode = (ws_size >= need) ? 1 : 0;

  k_prep<<<9440,256,0,stream>>>(bev, vfh, mode,
      m_w_in,m_wz,m_w0,m_w1,m_wo, g_w_in,g_wz,g_w0,g_w1,g_wo,
      pkM, pkG, (float*)d_out);
  k_fused<2><<<R/16,512,0,stream>>>(vfh,bev,mode,camK,pix,noise,unitb,vdirb,Tsi,dsort,pkG,
      g_b_in,g_bz,g_b0,g_b1,g_bo, means,stds,nullptr);
  k_fused<4><<<R,512,0,stream>>>(vfh,bev,mode,camK,pix,noise,unitb,vdirb,Tsi,dsort,pkM,
      m_b_in,m_bz,m_b0,m_b1,m_bo, means,stds,outbf);
  k_render<<<R/4,256,0,stream>>>(outbf,dsort,means,stds,unitb,img_s,img_t,pix,camK,Tst,
                                 (float*)d_out,R);
}

// Round 6
// 415.018 us; speedup vs baseline: 1.5553x; 1.5553x over previous
//
#include <hip/hip_runtime.h>

typedef __attribute__((ext_vector_type(8))) short short8;
typedef __attribute__((ext_vector_type(4))) float f32x4;
typedef __attribute__((ext_vector_type(2))) float f32x2;
typedef __attribute__((ext_vector_type(2))) unsigned u32x2;
typedef unsigned short ushort_t;

#define WIMG 1216
#define HIMG 352

__device__ __forceinline__ float sigmoid_(float x){ return 1.f/(1.f+__expf(-x)); }
__device__ __forceinline__ float softplus_(float x){
  return fmaxf(x,0.f) + log1pf(__expf(-fabsf(x)));
}
__device__ __forceinline__ ushort_t f2b(float x){
  union { float f; unsigned u; } v; v.f = x;
  unsigned r = v.u + 0x7FFF + ((v.u >> 16) & 1);
  return (ushort_t)(r >> 16);
}
__device__ __forceinline__ unsigned pack_trunc(float a, float b){
  union { float f; unsigned u; } va, vb; va.f = a; vb.f = b;
  return (va.u >> 16) | (vb.u & 0xFFFF0000u);
}
// RTNE packed f32->bf16x2 in one instruction (compiler can't derive from bit-tricks)
__device__ __forceinline__ unsigned cvt_pk_bf16(float a, float b){
  unsigned r;
  asm("v_cvt_pk_bf16_f32 %0, %1, %2" : "=v"(r) : "v"(a), "v"(b));
  return r;
}
__device__ __forceinline__ f32x2 bf2x(unsigned u){
  union { unsigned uu[2]; f32x2 f; } v;
  v.uu[0] = u << 16; v.uu[1] = u & 0xFFFF0000u;
  return v.f;
}

// ---------- combined prep: transpose (blocks 0..8191) + weight pack (blocks 8192..9439) ----------
// pack layout blocks 0..37: [w_in ks0,ks1][i: wz*4, w0*4, w1*4]*3 ; block 38: w_out 16-col padded
__global__ __launch_bounds__(256)
void k_prep(const float* __restrict__ bev, ushort_t* __restrict__ vfh, int mode,
            const float* __restrict__ mw_in, const float* __restrict__ mwz,
            const float* __restrict__ mw0, const float* __restrict__ mw1,
            const float* __restrict__ mwo,
            const float* __restrict__ gw_in, const float* __restrict__ gwz,
            const float* __restrict__ gw0, const float* __restrict__ gw1,
            const float* __restrict__ gwo,
            ushort_t* __restrict__ pkM, ushort_t* __restrict__ pkG,
            float* __restrict__ out0){
  int bx = blockIdx.x;
  int tid = threadIdx.x;
  if (bx < 8192) {
    if (!mode) return;
    __shared__ float tile[64][65];
    int y0 = (bx & 1) * 64;
    int c0 = ((bx >> 1) & 1) * 64;
    int zx = bx >> 2;
    const float* s = bev + (size_t)(zx >> 7)*2097152 + (size_t)c0*16384 + (size_t)(zx & 127)*128 + y0;
    int r0 = tid >> 4, f4 = tid & 15;
    #pragma unroll
    for (int it = 0; it < 4; ++it) {
      int c = it*16 + r0;
      f32x4 v = __builtin_nontemporal_load((const f32x4*)(s + (size_t)c*16384 + f4*4));
      tile[c][f4*4+0]=v.x; tile[c][f4*4+1]=v.y; tile[c][f4*4+2]=v.z; tile[c][f4*4+3]=v.w;
    }
    __syncthreads();
    ushort_t* d = vfh + ((size_t)zx*128 + y0)*128 + c0;
    #pragma unroll
    for (int it = 0; it < 4; ++it) {
      int y = it*16 + r0;
      u32x2 o;
      o.x = pack_trunc(tile[f4*4+0][y], tile[f4*4+1][y]);
      o.y = pack_trunc(tile[f4*4+2][y], tile[f4*4+3][y]);
      __builtin_nontemporal_store(o, (u32x2*)(d + (size_t)y*128 + f4*4));
    }
    return;
  }
  int pb = bx - 8192;                 // 0..1247 ; 624 per net
  if (pb == 0 && tid == 0) out0[0] = 0.f;
  int net = pb >= 624;                // 0 = M, 1 = G
  const float* w_in = net ? gw_in : mw_in;
  const float* wz   = net ? gwz   : mwz;
  const float* w0   = net ? gw0   : mw0;
  const float* w1   = net ? gw1   : mw1;
  const float* wo   = net ? gwo   : mwo;
  int outd = net ? 2 : 4;
  ushort_t* pk = net ? pkG : pkM;
  int id = (pb - (net ? 624 : 0))*256 + tid;
  if (id >= 39*4096) return;
  int blk = id >> 12;
  int e = id & 4095;
  float val = 0.f;
  if (blk < 38) {
    int nt = e >> 9, lane = (e >> 3) & 63, j = e & 7;
    int kloc = (lane >> 4)*8 + j;
    int n = nt*16 + (lane & 15);
    if (blk < 2) {
      int k = blk*32 + kloc;
      val = (k < 42) ? w_in[k*128 + n] : 0.f;
    } else {
      int g = blk - 2;
      int i = g / 12, r = g % 12, m = r >> 2, ks = r & 3;
      int k = ks*32 + kloc;
      const float* src = (m==0 ? wz : (m==1 ? w0 : w1)) + i*16384;
      val = src[k*128 + n];
    }
  } else if (e < 2048) {
    int ks = e >> 9, lane = (e >> 3) & 63, j = e & 7;
    int k = ks*32 + (lane >> 4)*8 + j;
    int n = lane & 15;
    val = (n < outd) ? wo[k*outd + n] : 0.f;
  }
  pk[id] = f2b(val);
}

// ---------- fragment GEMM, 2-ray blocks: 8 waves; wave = (cg: 32 channels) x (pg: 64 points) ----
// Per-wave register structure identical to the verified r1 kernel (acc[2][4], w[4][2]).
// acts (B) in LDS fragment order: frag = ks*8 + pg*4 + nt (32 frags of 512 ushort).
// SWZ: 16B-unit XOR swizzle (idx = l ^ (l>>3) ^ ks on low 3 bits) matching gather writes.
template<int KS, bool SWZ>
__device__ __forceinline__ void gemm_frag(const ushort_t* lds,
                                          const ushort_t* __restrict__ pkW,
                                          f32x4 acc[2][4], int cg, int pg, int lane)
{
  short8 w[KS][2];
  #pragma unroll
  for (int ks = 0; ks < KS; ++ks)
    #pragma unroll
    for (int ct = 0; ct < 2; ++ct)
      w[ks][ct] = *(const short8*)(pkW + (size_t)((ks*8 + cg*2 + ct)*64 + lane)*8);
  #pragma unroll
  for (int ks = 0; ks < KS; ++ks) {
    int idx = SWZ ? ((lane & ~7) | ((lane ^ (lane >> 3) ^ ks) & 7)) : lane;
    short8 b[4];
    #pragma unroll
    for (int nt = 0; nt < 4; ++nt)
      b[nt] = *(const short8*)(lds + (ks*8 + pg*4 + nt)*512 + idx*8);
    __builtin_amdgcn_s_setprio(1);
    #pragma unroll
    for (int ct = 0; ct < 2; ++ct)
      #pragma unroll
      for (int nt = 0; nt < 4; ++nt)
        acc[ct][nt] = __builtin_amdgcn_mfma_f32_16x16x32_bf16(w[ks][ct], b[nt], acc[ct][nt], 0,0,0);
    __builtin_amdgcn_s_setprio(0);
  }
}

// D: channel c = cg*32 + ct*16 + quad*4 + r ; point p = (pg*4+nt)*16 + l15
// fragment-order store: frag = cg*8 + pg*4 + nt ; lane' = (ct*2 + (quad>>1))*16 + l15 ; j = (quad&1)*4
__device__ __forceinline__ void store_reluF(ushort_t* buf, const f32x4 acc[2][4],
                                            int cg, int pg, int lane){
  int l15 = lane & 15, quad = lane >> 4;
  int j = (quad & 1)*4;
  #pragma unroll
  for (int ct = 0; ct < 2; ++ct) {
    int lp = (ct*2 + (quad >> 1))*16 + l15;
    #pragma unroll
    for (int nt = 0; nt < 4; ++nt) {
      uint2 o;
      o.x = cvt_pk_bf16(fmaxf(acc[ct][nt][0],0.f), fmaxf(acc[ct][nt][1],0.f));
      o.y = cvt_pk_bf16(fmaxf(acc[ct][nt][2],0.f), fmaxf(acc[ct][nt][3],0.f));
      *(uint2*)(buf + (cg*8 + pg*4 + nt)*512 + lp*8 + j) = o;
    }
  }
}

// ---------- fused: OUTD=2 gauss (rayinit + MLP + sort), OUTD=4 main (MLP) ----------
// 2 rays (128 points) per block, 512 threads = 8 waves; LDS 64 KB static -> 2 blocks/CU.
// Halves barrier events / setup / epilogue per ray vs the 1-ray block.
// Aux setup arrays overlay Wb (dead before PE writes Wb); sMean/sStd overlay zf at +8 KB.
template<int OUTD>
__global__ __launch_bounds__(512, 4)
void k_fused(const ushort_t* __restrict__ vfh, const float* __restrict__ vf0, int mode,
             const float* __restrict__ camK, const int* __restrict__ pix,
             const float* __restrict__ noise,
             float* __restrict__ unit, float* __restrict__ viewdir,
             const float* __restrict__ Tsi, float* __restrict__ dsort,
             const ushort_t* __restrict__ pk,
             const float* __restrict__ b_in, const float* __restrict__ bzv,
             const float* __restrict__ b0v, const float* __restrict__ b1v,
             const float* __restrict__ b_out,
             float* __restrict__ means, float* __restrict__ stds, float* __restrict__ outbuf)
{
  __shared__ __align__(16) ushort_t smem[32768];   // 65536 B
  ushort_t* zf = smem;             // 32 KB (32 frags)
  ushort_t* Wb = smem + 16384;     // 32 KB (32 frags)
  // aux overlay inside Wb (first ~6.8 KB) — dead before PE writes Wb
  float* auxf = (float*)Wb;
  int*   sOff = (int*)auxf;                          // [128]
  float (*sW)[8] = (float(*)[8])(auxf + 128);        // [128][8]
  float* sPx = auxf + 1152;                          // [128]
  float* sPy = auxf + 1280;
  float* sPz = auxf + 1408;
  float* sUx = auxf + 1536; float* sUy = auxf + 1568; float* sUz = auxf + 1600;  // [32]
  float* sVx = auxf + 1632; float* sVy = auxf + 1664; float* sVz = auxf + 1696;
  // sMean/sStd overlay zf at +8 KB (OUTD==2 only; sort's fbuf uses zf[0..8 KB))
  float* zff = (float*)zf;
  float* sMean = zff + 2048;                         // [128]
  float* sStd  = zff + 2176;                         // [128]

  int tid = threadIdx.x;
  int wv = tid >> 6, lane = tid & 63;
  int cg = wv & 3, pg = wv >> 2;
  int qbase = blockIdx.x * 128;

  if constexpr (OUTD == 2) {
    if (tid < 32) {
      int gray = (qbase >> 2) + tid;
      float a=camK[0],b=camK[1],c=camK[2],d=camK[3],e=camK[4],f=camK[5],g=camK[6],h=camK[7],i=camK[8];
      float c00 = e*i-f*h, c01 = c*h-b*i, c02 = b*f-c*e;
      float c10 = f*g-d*i, c11 = a*i-c*g, c12 = c*d-a*f;
      float c20 = d*h-e*g, c21 = b*g-a*h, c22 = a*e-b*d;
      float det = a*c00 + b*c10 + c*c20;
      float id = 1.f/det;
      float u = (float)pix[2*gray], v = (float)pix[2*gray+1];
      float dx = (c00*u + c01*v + c02)*id;
      float dy = (c10*u + c11*v + c12)*id;
      float dz = (c20*u + c21*v + c22)*id;
      float n = sqrtf(dx*dx+dy*dy+dz*dz);
      dx/=n; dy/=n; dz/=n;
      sUx[tid]=dx; sUy[tid]=dy; sUz[tid]=dz;
      unit[3*gray]=dx; unit[3*gray+1]=dy; unit[3*gray+2]=dz;
      float vx = Tsi[0]*dx + Tsi[1]*dy + Tsi[2]*dz;
      float vy = Tsi[4]*dx + Tsi[5]*dy + Tsi[6]*dz;
      float vz = Tsi[8]*dx + Tsi[9]*dy + Tsi[10]*dz;
      sVx[tid]=vx; sVy[tid]=vy; sVz[tid]=vz;
      viewdir[3*gray]=vx; viewdir[3*gray+1]=vy; viewdir[3*gray+2]=vz;
    }
  } else {
    if (tid < 2) {
      int ray = blockIdx.x*2 + tid;
      sUx[tid]=unit[3*ray]; sUy[tid]=unit[3*ray+1]; sUz[tid]=unit[3*ray+2];
      sVx[tid]=viewdir[3*ray]; sVy[tid]=viewdir[3*ray+1]; sVz[tid]=viewdir[3*ray+2];
    }
  }
  __syncthreads();

  if (tid < 128) {
    float t, ux, uy, uz;
    if constexpr (OUTD == 2) {
      t = ((float)(tid & 3) + 0.5f) * 25.f;
      int lr = tid >> 2;
      ux = sUx[lr]; uy = sUy[lr]; uz = sUz[lr];
    } else {
      t = dsort[qbase + tid];
      int lr = tid >> 6;
      ux = sUx[lr]; uy = sUy[lr]; uz = sUz[lr];
    }
    float wx=ux*t, wy=uy*t, wz=uz*t;
    float px = Tsi[0]*wx + Tsi[1]*wy + Tsi[2]*wz + Tsi[3];
    float py = Tsi[4]*wx + Tsi[5]*wy + Tsi[6]*wz + Tsi[7];
    float pz = Tsi[8]*wx + Tsi[9]*wy + Tsi[10]*wz + Tsi[11];
    sPx[tid]=px; sPy[tid]=py; sPz[tid]=pz;
    float gx = (px + 25.6f)*2.5f;
    float gy = (py + 25.6f)*2.5f;
    float gz = (pz + 2.0f)*2.5f;
    bool inb = (gx>=0.f)&&(gx<=127.f)&&(gy>=0.f)&&(gy<=127.f)&&(gz>=0.f)&&(gz<=15.f);
    gx = fminf(fmaxf(gx,0.f),127.f);
    gy = fminf(fmaxf(gy,0.f),127.f);
    gz = fminf(fmaxf(gz,0.f),15.f);
    int x0 = min(max((int)floorf(gx),0),126);
    int y0 = min(max((int)floorf(gy),0),126);
    int z0 = min(max((int)floorf(gz),0),14);
    float fx = gx-(float)x0, fy = gy-(float)y0, fz = gz-(float)z0;
    float sc = inb ? 1.f : 0.f;
    float ax0 = 1.f-fx, ay0 = 1.f-fy;
    float az0 = (1.f-fz)*sc, az1 = fz*sc;
    float q00 = ax0*ay0, q01 = ax0*fy, q10 = fx*ay0, q11 = fx*fy;
    sW[tid][0] = az0*q00; sW[tid][1] = az0*q01; sW[tid][2] = az0*q10; sW[tid][3] = az0*q11;
    sW[tid][4] = az1*q00; sW[tid][5] = az1*q01; sW[tid][6] = az1*q10; sW[tid][7] = az1*q11;
    sOff[tid] = mode ? (((z0*128 + x0)*128 + y0)*128)
                     : (z0*2097152 + x0*128 + y0);
  }
  __syncthreads();

  // trilinear gather -> zf in fragment order (XOR-swizzled 16B units), packed f32x2 math
  // 128 points x 16 channel-chunks = 2048 tasks / 512 threads = 4 iters
  for (int it = 0; it < 4; ++it) {
    int lin = it*512 + tid;
    int p = lin >> 4, cb = lin & 15;
    float4 wA = *(const float4*)&sW[p][0];
    float4 wB = *(const float4*)&sW[p][4];
    f32x2 r01={0.f,0.f}, r23={0.f,0.f}, r45={0.f,0.f}, r67={0.f,0.f};
    if (mode) {
      const ushort_t* b = vfh + sOff[p] + cb*8;
      uint4 v;
      #define ACC8(PTR, W) \
        v = *(const uint4*)(PTR); \
        r01 += (W)*bf2x(v.x); r23 += (W)*bf2x(v.y); \
        r45 += (W)*bf2x(v.z); r67 += (W)*bf2x(v.w);
      ACC8(b,                     wA.x)
      ACC8(b + 128,               wA.y)
      ACC8(b + 16384,             wA.z)
      ACC8(b + 16384 + 128,       wA.w)
      ACC8(b + 2097152,           wB.x)
      ACC8(b + 2097152 + 128,     wB.y)
      ACC8(b + 2097152 + 16384,   wB.z)
      ACC8(b + 2097152 + 16512,   wB.w)
      #undef ACC8
    } else {
      const float* bsrc = vf0 + sOff[p];
      float rr[8];
      #pragma unroll
      for (int k = 0; k < 8; ++k) {
        const float* bc = bsrc + (size_t)(cb*8 + k)*16384;
        rr[k] = wA.x*bc[0] + wA.y*bc[1] + wA.z*bc[128] + wA.w*bc[129]
              + wB.x*bc[2097152] + wB.y*bc[2097153] + wB.z*bc[2097280] + wB.w*bc[2097281];
      }
      r01 = (f32x2){rr[0],rr[1]}; r23 = (f32x2){rr[2],rr[3]};
      r45 = (f32x2){rr[4],rr[5]}; r67 = (f32x2){rr[6],rr[7]};
    }
    uint4 o;
    o.x = cvt_pk_bf16(r01.x, r01.y); o.y = cvt_pk_bf16(r23.x, r23.y);
    o.z = cvt_pk_bf16(r45.x, r45.y); o.w = cvt_pk_bf16(r67.x, r67.y);
    int T = (cb >> 2)*8 + (p >> 4);
    int lanep = (cb & 3)*16 + (p & 15);
    // write-side swizzle must match gemm_frag's read swizzle: ks = cb>>2 = T>>3
    int lsw = (lanep & ~7) | ((lanep ^ (lanep >> 3) ^ (cb >> 2)) & 7);
    *(uint4*)(zf + T*512 + lsw*8) = o;
  }

  // hoist this thread's PE coords out of the aux overlay BEFORE Wb is overwritten
  int pp = tid & 127;
  float ppx = sPx[pp], ppy = sPy[pp], ppz = sPz[pp];
  int plr = (OUTD == 2) ? (pp >> 2) : (pp >> 6);
  float pvx = sVx[plr], pvy = sVy[plr], pvz = sVz[plr];
  __syncthreads();   // all aux reads (gather + coords) complete; Wb may now be written

  // PE inputs -> Wb in fragment order (k=0..63, dims 42..63 zero)
  // 128 points x 8 dim-groups = 1024 tasks / 512 threads = 2 per thread
  {
    int p = pp, wv2 = tid >> 7;        // 0..3
    #pragma unroll
    for (int hf = 0; hf < 2; ++hf) {
      int g = hf*4 + wv2;              // 0..7
      float vals[8];
      #pragma unroll
      for (int j = 0; j < 8; ++j) {
        int d = g*8 + j;
        float val = 0.f;
        if (d < 3)      val = (d==0)?ppx:((d==1)?ppy:ppz);
        else if (d < 39) {
          int s = d - 3; bool isSin = (s < 18); if (!isSin) s -= 18;
          int axis = s/6, fi = s%6;
          float base = (axis==0)?ppx:((axis==1)?ppy:ppz);
          float arg = base * (float)(1 << fi);
          val = isSin ? __sinf(arg) : __cosf(arg);
        } else if (d < 42) {
          val = (d==39)?pvx:((d==40)?pvy:pvz);
        }
        vals[j] = val;
      }
      uint4 o;
      o.x = cvt_pk_bf16(vals[0], vals[1]);
      o.y = cvt_pk_bf16(vals[2], vals[3]);
      o.z = cvt_pk_bf16(vals[4], vals[5]);
      o.w = cvt_pk_bf16(vals[6], vals[7]);
      // frag = (g>>2)*8 + (p>>4); lane' = (g&3)*16 + (p&15)
      *(uint4*)(Wb + ((g>>2)*8 + (p>>4))*512 + (((g&3)*16 + (p&15)))*8) = o;
    }
  }
  __syncthreads();

  int l15 = lane & 15, quad = lane >> 4;
  int cbase = cg*32 + quad*4;       // channel base for ct=0 (ct=1 adds 16)

  f32x4 h[2][4];
  #pragma unroll
  for (int ct = 0; ct < 2; ++ct) {
    f32x4 bi = *(const f32x4*)(b_in + cbase + ct*16);
    #pragma unroll
    for (int nt = 0; nt < 4; ++nt) h[ct][nt] = bi;
  }
  gemm_frag<2,false>(Wb, pk, h, cg, pg, lane);

  const ushort_t* pkl = pk + 2*4096;
  #pragma unroll 1
  for (int i3 = 0; i3 < 3; ++i3) {
    gemm_frag<4,true>(zf, pkl + (size_t)(i3*12)*4096, h, cg, pg, lane);
    #pragma unroll
    for (int ct = 0; ct < 2; ++ct) {
      f32x4 bz = *(const f32x4*)(bzv + i3*128 + cbase + ct*16);
      #pragma unroll
      for (int nt = 0; nt < 4; ++nt) h[ct][nt] += bz;
    }
    __syncthreads();
    store_reluF(Wb, h, cg, pg, lane);
    __syncthreads();
    f32x4 net[2][4];
    #pragma unroll
    for (int ct = 0; ct < 2; ++ct) {
      f32x4 c0b = *(const f32x4*)(b0v + i3*128 + cbase + ct*16);
      #pragma unroll
      for (int nt = 0; nt < 4; ++nt) net[ct][nt] = c0b;
    }
    gemm_frag<4,false>(Wb, pkl + (size_t)(i3*12+4)*4096, net, cg, pg, lane);
    __syncthreads();
    store_reluF(Wb, net, cg, pg, lane);
    __syncthreads();
    gemm_frag<4,false>(Wb, pkl + (size_t)(i3*12+8)*4096, h, cg, pg, lane);
    #pragma unroll
    for (int ct = 0; ct < 2; ++ct) {
      f32x4 o1b = *(const f32x4*)(b1v + i3*128 + cbase + ct*16);
      #pragma unroll
      for (int nt = 0; nt < 4; ++nt) h[ct][nt] += o1b;
    }
  }
  __syncthreads();
  store_reluF(Wb, h, cg, pg, lane);
  __syncthreads();

  // epilogue: one 16x16 MFMA per wave; wave owns points wv*16..+15 (8 waves cover 128)
  {
    const ushort_t* pkw = pk + 38*4096;
    f32x4 oa = (f32x4){0.f,0.f,0.f,0.f};
    #pragma unroll
    for (int ks = 0; ks < 4; ++ks) {
      short8 w = *(const short8*)(pkw + (size_t)(ks*64 + lane)*8);
      short8 b = *(const short8*)(Wb + (ks*8 + wv)*512 + lane*8);
      oa = __builtin_amdgcn_mfma_f32_16x16x32_bf16(w, b, oa, 0,0,0);
    }
    if (quad == 0) {
      int lq = wv*16 + l15;
      int q = qbase + lq;
      if constexpr (OUTD == 4) {
        float4 o = { oa[0] + b_out[0], oa[1] + b_out[1], oa[2] + b_out[2], oa[3] + b_out[3] };
        *(float4*)(outbuf + (size_t)q*4) = o;
      } else {
        int g = q & 3;
        float m = fminf(fmaxf(((float)g + 0.5f)*25.f + oa[0] + b_out[0], 0.5f), 100.f);
        float sd = 2.5f*sigmoid_(oa[1] + b_out[1]) + 0.1f;
        means[q] = m; stds[q] = sd;
        sMean[lq] = m; sStd[lq] = sd;
      }
    }
  }

  // gauss: fused depth-set build + rank-sort (32 rays/block; all 512 threads)
  if constexpr (OUTD == 2) {
    __syncthreads();
    float* fbuf = zff;                 // zf[0..8 KB) — sMean/sStd live at +8 KB
    int lr = tid >> 4;                 // 0..31
    int sbase = (tid & 15) * 4;
    float vals[4];
    #pragma unroll
    for (int s = 0; s < 4; ++s) {
      int slot = sbase + s;
      float val;
      if (slot < 32) val = 0.5f + (float)slot * (99.5f/31.f);
      else {
        int idx = slot - 32, g = idx >> 3, sx = idx & 7;
        int lq = lr*4 + g;
        float mu = sMean[lq], sd = sStd[lq];
        val = fminf(fmaxf(mu + sd*noise[(size_t)(qbase + lq)*8 + sx], 0.5f), 100.f);
      }
      fbuf[lr*64 + slot] = val;
      vals[s] = val;
    }
    __syncthreads();
    int rk[4] = {0,0,0,0};
    for (int k = 0; k < 64; ++k) {
      float o = fbuf[lr*64 + k];
      #pragma unroll
      for (int s = 0; s < 4; ++s)
        rk[s] += (o < vals[s]) || (o == vals[s] && k < sbase + s);
    }
    int gray = (qbase >> 2) + lr;
    #pragma unroll
    for (int s = 0; s < 4; ++s)
      dsort[(size_t)gray*64 + rk[s]] = vals[s];
  }
}

// ---------- render + losses: one wave per ray, atomic total ----------
__device__ __forceinline__ void bilin3(const float* __restrict__ img, float u, float v, float* out){
  u = fminf(fmaxf(u, 0.f), (float)(WIMG-1));
  v = fminf(fmaxf(v, 0.f), (float)(HIMG-1));
  int u0 = min(max((int)floorf(u),0), WIMG-2);
  int v0 = min(max((int)floorf(v),0), HIMG-2);
  float fu = u - (float)u0, fv = v - (float)v0;
  float w00=(1.f-fv)*(1.f-fu), w01=(1.f-fv)*fu, w10=fv*(1.f-fu), w11=fv*fu;
  #pragma unroll
  for (int c = 0; c < 3; ++c) {
    const float* b = img + (size_t)c*(HIMG*WIMG) + (size_t)v0*WIMG + u0;
    out[c] = w00*b[0] + w01*b[1] + w10*b[WIMG] + w11*b[WIMG+1];
  }
}

__global__ void k_render(const float* __restrict__ outbuf, const float* __restrict__ dsort,
                         const float* __restrict__ means, const float* __restrict__ stds,
                         const float* __restrict__ unit,
                         const float* __restrict__ img_src, const float* __restrict__ img_tgt,
                         const int* __restrict__ pix, const float* __restrict__ camK,
                         const float* __restrict__ Tst, float* __restrict__ loss_out, int R){
  __shared__ float accw[4];
  int gid = blockIdx.x*blockDim.x + threadIdx.x;
  int r = gid >> 6, lane = gid & 63;
  float d = dsort[(size_t)r*64 + lane];
  float dn = __shfl_down(d, 1);
  float delta = (lane < 63) ? (dn - d) : 1e10f;
  float4 o = *(const float4*)(outbuf + (size_t)r*256 + lane*4);
  float sig = softplus_(o.x);
  float alpha = 1.f - __expf(-sig*delta);
  float om = 1.f - alpha + 1e-10f;
  float prod = om;
  #pragma unroll
  for (int off = 1; off < 64; off <<= 1) {
    float v = __shfl_up(prod, off);
    if (lane >= off) prod *= v;
  }
  float texc = __shfl_up(prod, 1);
  if (lane == 0) texc = 1.f;
  float w = alpha * texc;
  float m0=means[r*4],m1=means[r*4+1],m2=means[r*4+2],m3=means[r*4+3];
  float s0=stds[r*4], s1=stds[r*4+1], s2=stds[r*4+2], s3=stds[r*4+3];
  float t0=(d-m0)/s0, t1=(d-m1)/s1, t2=(d-m2)/s2, t3=(d-m3)/s3;
  float pm = 0.25f*0.3989422804014327f*(__expf(-0.5f*t0*t0)/s0 + __expf(-0.5f*t1*t1)/s1
                                      + __expf(-0.5f*t2*t2)/s2 + __expf(-0.5f*t3*t3)/s3);
  float kl  = w * (-__logf(pm + 1e-6f));
  float dep = w * d;
  float c0 = w * sigmoid_(o.y);
  float c1 = w * sigmoid_(o.z);
  float c2 = w * sigmoid_(o.w);
  #pragma unroll
  for (int off = 32; off; off >>= 1) {
    dep += __shfl_xor(dep, off);
    c0  += __shfl_xor(c0, off);
    c1  += __shfl_xor(c1, off);
    c2  += __shfl_xor(c2, off);
    kl  += __shfl_xor(kl, off);
  }
  if (lane == 0) {
    float ld = fminf(fminf(fabsf(m0-dep),fabsf(m1-dep)), fminf(fabsf(m2-dep),fabsf(m3-dep)));
    float src[3], tgt[3];
    float u = (float)pix[2*r], v = (float)pix[2*r+1];
    bilin3(img_src, u, v, src);
    float ux=unit[3*r],uy=unit[3*r+1],uz=unit[3*r+2];
    float pcx=ux*dep, pcy=uy*dep, pcz=uz*dep;
    float ptx = Tst[0]*pcx + Tst[1]*pcy + Tst[2]*pcz + Tst[3];
    float pty = Tst[4]*pcx + Tst[5]*pcy + Tst[6]*pcz + Tst[7];
    float ptz = Tst[8]*pcx + Tst[9]*pcy + Tst[10]*pcz + Tst[11];
    float prx = camK[0]*ptx + camK[1]*pty + camK[2]*ptz;
    float pry = camK[3]*ptx + camK[4]*pty + camK[5]*ptz;
    float prz = camK[6]*ptx + camK[7]*pty + camK[8]*ptz;
    prz = fmaxf(prz, 0.001f);
    bilin3(img_tgt, prx/prz, pry/prz, tgt);
    float lrepr = fabsf(src[0]-tgt[0])+fabsf(src[1]-tgt[1])+fabsf(src[2]-tgt[2]);
    float lcol  = fabsf(src[0]-c0)+fabsf(src[1]-c1)+fabsf(src[2]-c2);
    float invR = 1.f/(float)R;
    accw[threadIdx.x >> 6] = (lrepr + lcol) * (invR/3.f) + kl*invR + 0.01f*ld*invR;
  }
  __syncthreads();
  if (threadIdx.x == 0)
    atomicAdd(loss_out, accw[0]+accw[1]+accw[2]+accw[3]);
}

extern "C" void kernel_launch(void* const* d_in, const int* in_sizes, int n_in,
                              void* d_out, int out_size, void* d_ws, size_t ws_size,
                              hipStream_t stream)
{
  const float* bev   = (const float*)d_in[0];
  const float* camK  = (const float*)d_in[1];
  const float* img_s = (const float*)d_in[2];
  const float* img_t = (const float*)d_in[3];
  const float* Tsi   = (const float*)d_in[4];
  const float* Tst   = (const float*)d_in[5];
  const float* noise = (const float*)d_in[6];
  const int*   pix   = (const int*)d_in[7];
  const float* m_w_in=(const float*)d_in[8];  const float* m_b_in=(const float*)d_in[9];
  const float* m_wz  =(const float*)d_in[10]; const float* m_bz  =(const float*)d_in[11];
  const float* m_w0  =(const float*)d_in[12]; const float* m_b0  =(const float*)d_in[13];
  const float* m_w1  =(const float*)d_in[14]; const float* m_b1  =(const float*)d_in[15];
  const float* m_wo  =(const float*)d_in[16]; const float* m_bo  =(const float*)d_in[17];
  const float* g_w_in=(const float*)d_in[18]; const float* g_b_in=(const float*)d_in[19];
  const float* g_wz  =(const float*)d_in[20]; const float* g_bz  =(const float*)d_in[21];
  const float* g_w0  =(const float*)d_in[22]; const float* g_b0  =(const float*)d_in[23];
  const float* g_w1  =(const float*)d_in[24]; const float* g_b1  =(const float*)d_in[25];
  const float* g_wo  =(const float*)d_in[26]; const float* g_bo  =(const float*)d_in[27];

  int R = in_sizes[7] / 2;
  float* ws = (float*)d_ws;
  size_t off = 0;
  float* unitb = ws + off; off += (size_t)R*3;
  float* vdirb = ws + off; off += (size_t)R*3;
  float* means = ws + off; off += (size_t)R*4;
  float* stds  = ws + off; off += (size_t)R*4;
  float* dsort = ws + off; off += (size_t)R*64;
  float* outbf = ws + off; off += (size_t)R*256;
  ushort_t* pkM = (ushort_t*)(ws + off);
  ushort_t* pkG = pkM + 39*4096;
  off += 39*4096 + 64;
  off = (off + 63) & ~(size_t)63;
  ushort_t* vfh = (ushort_t*)(ws + off);
  size_t need = off*4ull + (size_t)16*128*128*128*2ull;
  int mode = (ws_size >= need) ? 1 : 0;

  k_prep<<<9440,256,0,stream>>>(bev, vfh, mode,
      m_w_in,m_wz,m_w0,m_w1,m_wo, g_w_in,g_wz,g_w0,g_w1,g_wo,
      pkM, pkG, (float*)d_out);
  k_fused<2><<<R/32,512,0,stream>>>(vfh,bev,mode,camK,pix,noise,unitb,vdirb,Tsi,dsort,pkG,
      g_b_in,g_bz,g_b0,g_b1,g_bo, means,stds,nullptr);
  k_fused<4><<<R/2,512,0,stream>>>(vfh,bev,mode,camK,pix,noise,unitb,vdirb,Tsi,dsort,pkM,
      m_b_in,m_bz,m_b0,m_b1,m_bo, means,stds,outbf);
  k_render<<<R/4,256,0,stream>>>(outbf,dsort,means,stds,unitb,img_s,img_t,pix,camK,Tst,
                                 (float*)d_out,R);
}

// Round 7
// 409.914 us; speedup vs baseline: 1.5746x; 1.0125x over previous
//
#include <hip/hip_runtime.h>

typedef __attribute__((ext_vector_type(8))) short short8;
typedef __attribute__((ext_vector_type(4))) float f32x4;
typedef __attribute__((ext_vector_type(2))) float f32x2;
typedef __attribute__((ext_vector_type(2))) unsigned u32x2;
typedef unsigned short ushort_t;

#define WIMG 1216
#define HIMG 352

__device__ __forceinline__ float sigmoid_(float x){ return 1.f/(1.f+__expf(-x)); }
__device__ __forceinline__ float softplus_(float x){
  return fmaxf(x,0.f) + log1pf(__expf(-fabsf(x)));
}
__device__ __forceinline__ ushort_t f2b(float x){
  union { float f; unsigned u; } v; v.f = x;
  unsigned r = v.u + 0x7FFF + ((v.u >> 16) & 1);
  return (ushort_t)(r >> 16);
}
__device__ __forceinline__ unsigned pack_trunc(float a, float b){
  union { float f; unsigned u; } va, vb; va.f = a; vb.f = b;
  return (va.u >> 16) | (vb.u & 0xFFFF0000u);
}
// RTNE packed f32->bf16x2 in one instruction (compiler can't derive from bit-tricks)
__device__ __forceinline__ unsigned cvt_pk_bf16(float a, float b){
  unsigned r;
  asm("v_cvt_pk_bf16_f32 %0, %1, %2" : "=v"(r) : "v"(a), "v"(b));
  return r;
}
__device__ __forceinline__ f32x2 bf2x(unsigned u){
  union { unsigned uu[2]; f32x2 f; } v;
  v.uu[0] = u << 16; v.uu[1] = u & 0xFFFF0000u;
  return v.f;
}

__device__ __forceinline__ void bilin3(const float* __restrict__ img, float u, float v, float* out){
  u = fminf(fmaxf(u, 0.f), (float)(WIMG-1));
  v = fminf(fmaxf(v, 0.f), (float)(HIMG-1));
  int u0 = min(max((int)floorf(u),0), WIMG-2);
  int v0 = min(max((int)floorf(v),0), HIMG-2);
  float fu = u - (float)u0, fv = v - (float)v0;
  float w00=(1.f-fv)*(1.f-fu), w01=(1.f-fv)*fu, w10=fv*(1.f-fu), w11=fv*fu;
  #pragma unroll
  for (int c = 0; c < 3; ++c) {
    const float* b = img + (size_t)c*(HIMG*WIMG) + (size_t)v0*WIMG + u0;
    out[c] = w00*b[0] + w01*b[1] + w10*b[WIMG] + w11*b[WIMG+1];
  }
}

// ---------- combined prep: transpose (blocks 0..8191) + weight pack (blocks 8192..9439) ----------
// pack layout blocks 0..37: [w_in ks0,ks1][i: wz*4, w0*4, w1*4]*3 ; block 38: w_out 16-col padded
__global__ __launch_bounds__(256)
void k_prep(const float* __restrict__ bev, ushort_t* __restrict__ vfh, int mode,
            const float* __restrict__ mw_in, const float* __restrict__ mwz,
            const float* __restrict__ mw0, const float* __restrict__ mw1,
            const float* __restrict__ mwo,
            const float* __restrict__ gw_in, const float* __restrict__ gwz,
            const float* __restrict__ gw0, const float* __restrict__ gw1,
            const float* __restrict__ gwo,
            ushort_t* __restrict__ pkM, ushort_t* __restrict__ pkG,
            float* __restrict__ out0){
  int bx = blockIdx.x;
  int tid = threadIdx.x;
  if (bx < 8192) {
    if (!mode) return;
    __shared__ float tile[64][65];
    int y0 = (bx & 1) * 64;
    int c0 = ((bx >> 1) & 1) * 64;
    int zx = bx >> 2;
    const float* s = bev + (size_t)(zx >> 7)*2097152 + (size_t)c0*16384 + (size_t)(zx & 127)*128 + y0;
    int r0 = tid >> 4, f4 = tid & 15;
    #pragma unroll
    for (int it = 0; it < 4; ++it) {
      int c = it*16 + r0;
      f32x4 v = __builtin_nontemporal_load((const f32x4*)(s + (size_t)c*16384 + f4*4));
      tile[c][f4*4+0]=v.x; tile[c][f4*4+1]=v.y; tile[c][f4*4+2]=v.z; tile[c][f4*4+3]=v.w;
    }
    __syncthreads();
    ushort_t* d = vfh + ((size_t)zx*128 + y0)*128 + c0;
    #pragma unroll
    for (int it = 0; it < 4; ++it) {
      int y = it*16 + r0;
      u32x2 o;
      o.x = pack_trunc(tile[f4*4+0][y], tile[f4*4+1][y]);
      o.y = pack_trunc(tile[f4*4+2][y], tile[f4*4+3][y]);
      __builtin_nontemporal_store(o, (u32x2*)(d + (size_t)y*128 + f4*4));
    }
    return;
  }
  int pb = bx - 8192;                 // 0..1247 ; 624 per net
  if (pb == 0 && tid == 0) out0[0] = 0.f;
  int net = pb >= 624;                // 0 = M, 1 = G
  const float* w_in = net ? gw_in : mw_in;
  const float* wz   = net ? gwz   : mwz;
  const float* w0   = net ? gw0   : mw0;
  const float* w1   = net ? gw1   : mw1;
  const float* wo   = net ? gwo   : mwo;
  int outd = net ? 2 : 4;
  ushort_t* pk = net ? pkG : pkM;
  int id = (pb - (net ? 624 : 0))*256 + tid;
  if (id >= 39*4096) return;
  int blk = id >> 12;
  int e = id & 4095;
  float val = 0.f;
  if (blk < 38) {
    int nt = e >> 9, lane = (e >> 3) & 63, j = e & 7;
    int kloc = (lane >> 4)*8 + j;
    int n = nt*16 + (lane & 15);
    if (blk < 2) {
      int k = blk*32 + kloc;
      val = (k < 42) ? w_in[k*128 + n] : 0.f;
    } else {
      int g = blk - 2;
      int i = g / 12, r = g % 12, m = r >> 2, ks = r & 3;
      int k = ks*32 + kloc;
      const float* src = (m==0 ? wz : (m==1 ? w0 : w1)) + i*16384;
      val = src[k*128 + n];
    }
  } else if (e < 2048) {
    int ks = e >> 9, lane = (e >> 3) & 63, j = e & 7;
    int k = ks*32 + (lane >> 4)*8 + j;
    int n = lane & 15;
    val = (n < outd) ? wo[k*outd + n] : 0.f;
  }
  pk[id] = f2b(val);
}

// ---------- fragment GEMM, 2-ray blocks: 8 waves; wave = (cg: 32 channels) x (pg: 64 points) ----
// Per-wave register structure identical to the verified r1 kernel (acc[2][4], w[4][2]).
// acts (B) in LDS fragment order: frag = ks*8 + pg*4 + nt (32 frags of 512 ushort).
// SWZ: 16B-unit XOR swizzle (idx = l ^ (l>>3) ^ ks on low 3 bits) matching gather writes.
template<int KS, bool SWZ>
__device__ __forceinline__ void gemm_frag(const ushort_t* lds,
                                          const ushort_t* __restrict__ pkW,
                                          f32x4 acc[2][4], int cg, int pg, int lane)
{
  short8 w[KS][2];
  #pragma unroll
  for (int ks = 0; ks < KS; ++ks)
    #pragma unroll
    for (int ct = 0; ct < 2; ++ct)
      w[ks][ct] = *(const short8*)(pkW + (size_t)((ks*8 + cg*2 + ct)*64 + lane)*8);
  #pragma unroll
  for (int ks = 0; ks < KS; ++ks) {
    int idx = SWZ ? ((lane & ~7) | ((lane ^ (lane >> 3) ^ ks) & 7)) : lane;
    short8 b[4];
    #pragma unroll
    for (int nt = 0; nt < 4; ++nt)
      b[nt] = *(const short8*)(lds + (ks*8 + pg*4 + nt)*512 + idx*8);
    __builtin_amdgcn_s_setprio(1);
    #pragma unroll
    for (int ct = 0; ct < 2; ++ct)
      #pragma unroll
      for (int nt = 0; nt < 4; ++nt)
        acc[ct][nt] = __builtin_amdgcn_mfma_f32_16x16x32_bf16(w[ks][ct], b[nt], acc[ct][nt], 0,0,0);
    __builtin_amdgcn_s_setprio(0);
  }
}

// D: channel c = cg*32 + ct*16 + quad*4 + r ; point p = (pg*4+nt)*16 + l15
// fragment-order store: frag = cg*8 + pg*4 + nt ; lane' = (ct*2 + (quad>>1))*16 + l15 ; j = (quad&1)*4
__device__ __forceinline__ void store_reluF(ushort_t* buf, const f32x4 acc[2][4],
                                            int cg, int pg, int lane){
  int l15 = lane & 15, quad = lane >> 4;
  int j = (quad & 1)*4;
  #pragma unroll
  for (int ct = 0; ct < 2; ++ct) {
    int lp = (ct*2 + (quad >> 1))*16 + l15;
    #pragma unroll
    for (int nt = 0; nt < 4; ++nt) {
      uint2 o;
      o.x = cvt_pk_bf16(fmaxf(acc[ct][nt][0],0.f), fmaxf(acc[ct][nt][1],0.f));
      o.y = cvt_pk_bf16(fmaxf(acc[ct][nt][2],0.f), fmaxf(acc[ct][nt][3],0.f));
      *(uint2*)(buf + (cg*8 + pg*4 + nt)*512 + lp*8 + j) = o;
    }
  }
}

// ---------- fused: OUTD=2 gauss (rayinit + MLP + sort), OUTD=4 main (MLP + render + loss) ----------
// 2 rays (128 points) per block, 512 threads = 8 waves; LDS 64 KB static -> 2 blocks/CU.
// OUTD=4 tail: epilogue stages per-point float4 into dead zf, waves 0/1 run the full
// render+loss (wave-scan transmittance, KL, bilin3, reproj) and one atomicAdd per block.
// Eliminates the separate k_render dispatch and the outbuf round-trip.
template<int OUTD>
__global__ __launch_bounds__(512, 4)
void k_fused(const ushort_t* __restrict__ vfh, const float* __restrict__ vf0, int mode,
             const float* __restrict__ camK, const int* __restrict__ pix,
             const float* __restrict__ noise,
             float* __restrict__ unit, float* __restrict__ viewdir,
             const float* __restrict__ Tsi, float* __restrict__ dsort,
             const ushort_t* __restrict__ pk,
             const float* __restrict__ b_in, const float* __restrict__ bzv,
             const float* __restrict__ b0v, const float* __restrict__ b1v,
             const float* __restrict__ b_out,
             float* __restrict__ means, float* __restrict__ stds, float* __restrict__ lossp,
             const float* __restrict__ img_src, const float* __restrict__ img_tgt,
             const float* __restrict__ Tst)
{
  __shared__ __align__(16) ushort_t smem[32768];   // 65536 B
  ushort_t* zf = smem;             // 32 KB (32 frags)
  ushort_t* Wb = smem + 16384;     // 32 KB (32 frags)
  // aux overlay inside Wb (first ~6.8 KB) — dead before PE writes Wb
  float* auxf = (float*)Wb;
  int*   sOff = (int*)auxf;                          // [128]
  float (*sW)[8] = (float(*)[8])(auxf + 128);        // [128][8]
  float* sPx = auxf + 1152;                          // [128]
  float* sPy = auxf + 1280;
  float* sPz = auxf + 1408;
  float* sUx = auxf + 1536; float* sUy = auxf + 1568; float* sUz = auxf + 1600;  // [32]
  float* sVx = auxf + 1632; float* sVy = auxf + 1664; float* sVz = auxf + 1696;
  // sMean/sStd overlay zf at +8 KB (OUTD==2 only; sort's fbuf uses zf[0..8 KB))
  float* zff = (float*)zf;
  float* sMean = zff + 2048;                         // [128]
  float* sStd  = zff + 2176;                         // [128]

  int tid = threadIdx.x;
  int wv = tid >> 6, lane = tid & 63;
  int cg = wv & 3, pg = wv >> 2;
  int qbase = blockIdx.x * 128;

  if constexpr (OUTD == 2) {
    if (tid < 32) {
      int gray = (qbase >> 2) + tid;
      float a=camK[0],b=camK[1],c=camK[2],d=camK[3],e=camK[4],f=camK[5],g=camK[6],h=camK[7],i=camK[8];
      float c00 = e*i-f*h, c01 = c*h-b*i, c02 = b*f-c*e;
      float c10 = f*g-d*i, c11 = a*i-c*g, c12 = c*d-a*f;
      float c20 = d*h-e*g, c21 = b*g-a*h, c22 = a*e-b*d;
      float det = a*c00 + b*c10 + c*c20;
      float id = 1.f/det;
      float u = (float)pix[2*gray], v = (float)pix[2*gray+1];
      float dx = (c00*u + c01*v + c02)*id;
      float dy = (c10*u + c11*v + c12)*id;
      float dz = (c20*u + c21*v + c22)*id;
      float n = sqrtf(dx*dx+dy*dy+dz*dz);
      dx/=n; dy/=n; dz/=n;
      sUx[tid]=dx; sUy[tid]=dy; sUz[tid]=dz;
      unit[3*gray]=dx; unit[3*gray+1]=dy; unit[3*gray+2]=dz;
      float vx = Tsi[0]*dx + Tsi[1]*dy + Tsi[2]*dz;
      float vy = Tsi[4]*dx + Tsi[5]*dy + Tsi[6]*dz;
      float vz = Tsi[8]*dx + Tsi[9]*dy + Tsi[10]*dz;
      sVx[tid]=vx; sVy[tid]=vy; sVz[tid]=vz;
      viewdir[3*gray]=vx; viewdir[3*gray+1]=vy; viewdir[3*gray+2]=vz;
    }
  } else {
    if (tid < 2) {
      int ray = blockIdx.x*2 + tid;
      sUx[tid]=unit[3*ray]; sUy[tid]=unit[3*ray+1]; sUz[tid]=unit[3*ray+2];
      sVx[tid]=viewdir[3*ray]; sVy[tid]=viewdir[3*ray+1]; sVz[tid]=viewdir[3*ray+2];
    }
  }
  __syncthreads();

  float tval = 0.f;                       // waves 0/1 keep their point's depth for the render tail
  if (tid < 128) {
    float t, ux, uy, uz;
    if constexpr (OUTD == 2) {
      t = ((float)(tid & 3) + 0.5f) * 25.f;
      int lr = tid >> 2;
      ux = sUx[lr]; uy = sUy[lr]; uz = sUz[lr];
    } else {
      t = dsort[qbase + tid];
      int lr = tid >> 6;
      ux = sUx[lr]; uy = sUy[lr]; uz = sUz[lr];
    }
    tval = t;
    float wx=ux*t, wy=uy*t, wz=uz*t;
    float px = Tsi[0]*wx + Tsi[1]*wy + Tsi[2]*wz + Tsi[3];
    float py = Tsi[4]*wx + Tsi[5]*wy + Tsi[6]*wz + Tsi[7];
    float pz = Tsi[8]*wx + Tsi[9]*wy + Tsi[10]*wz + Tsi[11];
    sPx[tid]=px; sPy[tid]=py; sPz[tid]=pz;
    float gx = (px + 25.6f)*2.5f;
    float gy = (py + 25.6f)*2.5f;
    float gz = (pz + 2.0f)*2.5f;
    bool inb = (gx>=0.f)&&(gx<=127.f)&&(gy>=0.f)&&(gy<=127.f)&&(gz>=0.f)&&(gz<=15.f);
    gx = fminf(fmaxf(gx,0.f),127.f);
    gy = fminf(fmaxf(gy,0.f),127.f);
    gz = fminf(fmaxf(gz,0.f),15.f);
    int x0 = min(max((int)floorf(gx),0),126);
    int y0 = min(max((int)floorf(gy),0),126);
    int z0 = min(max((int)floorf(gz),0),14);
    float fx = gx-(float)x0, fy = gy-(float)y0, fz = gz-(float)z0;
    float sc = inb ? 1.f : 0.f;
    float ax0 = 1.f-fx, ay0 = 1.f-fy;
    float az0 = (1.f-fz)*sc, az1 = fz*sc;
    float q00 = ax0*ay0, q01 = ax0*fy, q10 = fx*ay0, q11 = fx*fy;
    sW[tid][0] = az0*q00; sW[tid][1] = az0*q01; sW[tid][2] = az0*q10; sW[tid][3] = az0*q11;
    sW[tid][4] = az1*q00; sW[tid][5] = az1*q01; sW[tid][6] = az1*q10; sW[tid][7] = az1*q11;
    sOff[tid] = mode ? (((z0*128 + x0)*128 + y0)*128)
                     : (z0*2097152 + x0*128 + y0);
  }
  __syncthreads();

  // trilinear gather -> zf in fragment order (XOR-swizzled 16B units), packed f32x2 math
  // 128 points x 16 channel-chunks = 2048 tasks / 512 threads = 4 iters
  for (int it = 0; it < 4; ++it) {
    int lin = it*512 + tid;
    int p = lin >> 4, cb = lin & 15;
    float4 wA = *(const float4*)&sW[p][0];
    float4 wB = *(const float4*)&sW[p][4];
    f32x2 r01={0.f,0.f}, r23={0.f,0.f}, r45={0.f,0.f}, r67={0.f,0.f};
    if (mode) {
      const ushort_t* b = vfh + sOff[p] + cb*8;
      uint4 v;
      #define ACC8(PTR, W) \
        v = *(const uint4*)(PTR); \
        r01 += (W)*bf2x(v.x); r23 += (W)*bf2x(v.y); \
        r45 += (W)*bf2x(v.z); r67 += (W)*bf2x(v.w);
      ACC8(b,                     wA.x)
      ACC8(b + 128,               wA.y)
      ACC8(b + 16384,             wA.z)
      ACC8(b + 16384 + 128,       wA.w)
      ACC8(b + 2097152,           wB.x)
      ACC8(b + 2097152 + 128,     wB.y)
      ACC8(b + 2097152 + 16384,   wB.z)
      ACC8(b + 2097152 + 16512,   wB.w)
      #undef ACC8
    } else {
      const float* bsrc = vf0 + sOff[p];
      float rr[8];
      #pragma unroll
      for (int k = 0; k < 8; ++k) {
        const float* bc = bsrc + (size_t)(cb*8 + k)*16384;
        rr[k] = wA.x*bc[0] + wA.y*bc[1] + wA.z*bc[128] + wA.w*bc[129]
              + wB.x*bc[2097152] + wB.y*bc[2097153] + wB.z*bc[2097280] + wB.w*bc[2097281];
      }
      r01 = (f32x2){rr[0],rr[1]}; r23 = (f32x2){rr[2],rr[3]};
      r45 = (f32x2){rr[4],rr[5]}; r67 = (f32x2){rr[6],rr[7]};
    }
    uint4 o;
    o.x = cvt_pk_bf16(r01.x, r01.y); o.y = cvt_pk_bf16(r23.x, r23.y);
    o.z = cvt_pk_bf16(r45.x, r45.y); o.w = cvt_pk_bf16(r67.x, r67.y);
    int T = (cb >> 2)*8 + (p >> 4);
    int lanep = (cb & 3)*16 + (p & 15);
    // write-side swizzle must match gemm_frag's read swizzle: ks = cb>>2 = T>>3
    int lsw = (lanep & ~7) | ((lanep ^ (lanep >> 3) ^ (cb >> 2)) & 7);
    *(uint4*)(zf + T*512 + lsw*8) = o;
  }

  // hoist this thread's PE coords out of the aux overlay BEFORE Wb is overwritten
  int pp = tid & 127;
  float ppx = sPx[pp], ppy = sPy[pp], ppz = sPz[pp];
  int plr = (OUTD == 2) ? (pp >> 2) : (pp >> 6);
  float pvx = sVx[plr], pvy = sVy[plr], pvz = sVz[plr];
  __syncthreads();   // all aux reads (gather + coords) complete; Wb may now be written

  // PE inputs -> Wb in fragment order (k=0..63, dims 42..63 zero)
  // 128 points x 8 dim-groups = 1024 tasks / 512 threads = 2 per thread
  {
    int p = pp, wv2 = tid >> 7;        // 0..3
    #pragma unroll
    for (int hf = 0; hf < 2; ++hf) {
      int g = hf*4 + wv2;              // 0..7
      float vals[8];
      #pragma unroll
      for (int j = 0; j < 8; ++j) {
        int d = g*8 + j;
        float val = 0.f;
        if (d < 3)      val = (d==0)?ppx:((d==1)?ppy:ppz);
        else if (d < 39) {
          int s = d - 3; bool isSin = (s < 18); if (!isSin) s -= 18;
          int axis = s/6, fi = s%6;
          float base = (axis==0)?ppx:((axis==1)?ppy:ppz);
          float arg = base * (float)(1 << fi);
          val = isSin ? __sinf(arg) : __cosf(arg);
        } else if (d < 42) {
          val = (d==39)?pvx:((d==40)?pvy:pvz);
        }
        vals[j] = val;
      }
      uint4 o;
      o.x = cvt_pk_bf16(vals[0], vals[1]);
      o.y = cvt_pk_bf16(vals[2], vals[3]);
      o.z = cvt_pk_bf16(vals[4], vals[5]);
      o.w = cvt_pk_bf16(vals[6], vals[7]);
      // frag = (g>>2)*8 + (p>>4); lane' = (g&3)*16 + (p&15)
      *(uint4*)(Wb + ((g>>2)*8 + (p>>4))*512 + (((g&3)*16 + (p&15)))*8) = o;
    }
  }
  __syncthreads();

  int l15 = lane & 15, quad = lane >> 4;
  int cbase = cg*32 + quad*4;       // channel base for ct=0 (ct=1 adds 16)

  f32x4 h[2][4];
  #pragma unroll
  for (int ct = 0; ct < 2; ++ct) {
    f32x4 bi = *(const f32x4*)(b_in + cbase + ct*16);
    #pragma unroll
    for (int nt = 0; nt < 4; ++nt) h[ct][nt] = bi;
  }
  gemm_frag<2,false>(Wb, pk, h, cg, pg, lane);

  const ushort_t* pkl = pk + 2*4096;
  #pragma unroll 1
  for (int i3 = 0; i3 < 3; ++i3) {
    gemm_frag<4,true>(zf, pkl + (size_t)(i3*12)*4096, h, cg, pg, lane);
    #pragma unroll
    for (int ct = 0; ct < 2; ++ct) {
      f32x4 bz = *(const f32x4*)(bzv + i3*128 + cbase + ct*16);
      #pragma unroll
      for (int nt = 0; nt < 4; ++nt) h[ct][nt] += bz;
    }
    __syncthreads();
    store_reluF(Wb, h, cg, pg, lane);
    __syncthreads();
    f32x4 net[2][4];
    #pragma unroll
    for (int ct = 0; ct < 2; ++ct) {
      f32x4 c0b = *(const f32x4*)(b0v + i3*128 + cbase + ct*16);
      #pragma unroll
      for (int nt = 0; nt < 4; ++nt) net[ct][nt] = c0b;
    }
    gemm_frag<4,false>(Wb, pkl + (size_t)(i3*12+4)*4096, net, cg, pg, lane);
    __syncthreads();
    store_reluF(Wb, net, cg, pg, lane);
    __syncthreads();
    gemm_frag<4,false>(Wb, pkl + (size_t)(i3*12+8)*4096, h, cg, pg, lane);
    #pragma unroll
    for (int ct = 0; ct < 2; ++ct) {
      f32x4 o1b = *(const f32x4*)(b1v + i3*128 + cbase + ct*16);
      #pragma unroll
      for (int nt = 0; nt < 4; ++nt) h[ct][nt] += o1b;
    }
  }
  __syncthreads();
  store_reluF(Wb, h, cg, pg, lane);
  __syncthreads();

  // epilogue: one 16x16 MFMA per wave; wave owns points wv*16..+15 (8 waves cover 128)
  // OUTD=4: stage per-point float4 into dead zf (2 KB) for the in-block render
  {
    const ushort_t* pkw = pk + 38*4096;
    f32x4 oa = (f32x4){0.f,0.f,0.f,0.f};
    #pragma unroll
    for (int ks = 0; ks < 4; ++ks) {
      short8 w = *(const short8*)(pkw + (size_t)(ks*64 + lane)*8);
      short8 b = *(const short8*)(Wb + (ks*8 + wv)*512 + lane*8);
      oa = __builtin_amdgcn_mfma_f32_16x16x32_bf16(w, b, oa, 0,0,0);
    }
    if (quad == 0) {
      int lq = wv*16 + l15;
      int q = qbase + lq;
      if constexpr (OUTD == 4) {
        float4 o = { oa[0] + b_out[0], oa[1] + b_out[1], oa[2] + b_out[2], oa[3] + b_out[3] };
        ((float4*)zf)[lq] = o;
      } else {
        int g = q & 3;
        float m = fminf(fmaxf(((float)g + 0.5f)*25.f + oa[0] + b_out[0], 0.5f), 100.f);
        float sd = 2.5f*sigmoid_(oa[1] + b_out[1]) + 0.1f;
        means[q] = m; stds[q] = sd;
        sMean[lq] = m; sStd[lq] = sd;
      }
    }
  }

  // render + losses (OUTD=4): waves 0/1 each own one ray (lane = sorted point index)
  if constexpr (OUTD == 4) {
    float* accw = (float*)(zf + 1024);   // bytes 2048.. — past the 128*float4 sO area
    __syncthreads();                     // sO visible
    if (wv < 2) {
      int ray = blockIdx.x*2 + wv;
      float d = tval;
      float dn = __shfl_down(d, 1);
      float delta = (lane < 63) ? (dn - d) : 1e10f;
      float4 o = ((const float4*)zf)[wv*64 + lane];
      float sig = softplus_(o.x);
      float alpha = 1.f - __expf(-sig*delta);
      float om = 1.f - alpha + 1e-10f;
      float prod = om;
      #pragma unroll
      for (int off = 1; off < 64; off <<= 1) {
        float v = __shfl_up(prod, off);
        if (lane >= off) prod *= v;
      }
      float texc = __shfl_up(prod, 1);
      if (lane == 0) texc = 1.f;
      float w = alpha * texc;
      float m0=means[ray*4],m1=means[ray*4+1],m2=means[ray*4+2],m3=means[ray*4+3];
      float s0=stds[ray*4], s1=stds[ray*4+1], s2=stds[ray*4+2], s3=stds[ray*4+3];
      float t0=(d-m0)/s0, t1=(d-m1)/s1, t2=(d-m2)/s2, t3=(d-m3)/s3;
      float pm = 0.25f*0.3989422804014327f*(__expf(-0.5f*t0*t0)/s0 + __expf(-0.5f*t1*t1)/s1
                                          + __expf(-0.5f*t2*t2)/s2 + __expf(-0.5f*t3*t3)/s3);
      float kl  = w * (-__logf(pm + 1e-6f));
      float dep = w * d;
      float c0 = w * sigmoid_(o.y);
      float c1 = w * sigmoid_(o.z);
      float c2 = w * sigmoid_(o.w);
      #pragma unroll
      for (int off = 32; off; off >>= 1) {
        dep += __shfl_xor(dep, off);
        c0  += __shfl_xor(c0, off);
        c1  += __shfl_xor(c1, off);
        c2  += __shfl_xor(c2, off);
        kl  += __shfl_xor(kl, off);
      }
      if (lane == 0) {
        float ld = fminf(fminf(fabsf(m0-dep),fabsf(m1-dep)), fminf(fabsf(m2-dep),fabsf(m3-dep)));
        float src[3], tgt[3];
        float u = (float)pix[2*ray], v = (float)pix[2*ray+1];
        bilin3(img_src, u, v, src);
        float ux=unit[3*ray],uy=unit[3*ray+1],uz=unit[3*ray+2];
        float pcx=ux*dep, pcy=uy*dep, pcz=uz*dep;
        float ptx = Tst[0]*pcx + Tst[1]*pcy + Tst[2]*pcz + Tst[3];
        float pty = Tst[4]*pcx + Tst[5]*pcy + Tst[6]*pcz + Tst[7];
        float ptz = Tst[8]*pcx + Tst[9]*pcy + Tst[10]*pcz + Tst[11];
        float prx = camK[0]*ptx + camK[1]*pty + camK[2]*ptz;
        float pry = camK[3]*ptx + camK[4]*pty + camK[5]*ptz;
        float prz = camK[6]*ptx + camK[7]*pty + camK[8]*ptz;
        prz = fmaxf(prz, 0.001f);
        bilin3(img_tgt, prx/prz, pry/prz, tgt);
        float lrepr = fabsf(src[0]-tgt[0])+fabsf(src[1]-tgt[1])+fabsf(src[2]-tgt[2]);
        float lcol  = fabsf(src[0]-c0)+fabsf(src[1]-c1)+fabsf(src[2]-c2);
        float invR = 1.f/(float)(gridDim.x*2);
        accw[wv] = (lrepr + lcol) * (invR/3.f) + kl*invR + 0.01f*ld*invR;
      }
    }
    __syncthreads();                     // accw visible
    if (tid == 0) atomicAdd(lossp, accw[0]+accw[1]);
  }

  // gauss: fused depth-set build + rank-sort (32 rays/block; all 512 threads)
  if constexpr (OUTD == 2) {
    __syncthreads();
    float* fbuf = zff;                 // zf[0..8 KB) — sMean/sStd live at +8 KB
    int lr = tid >> 4;                 // 0..31
    int sbase = (tid & 15) * 4;
    float vals[4];
    #pragma unroll
    for (int s = 0; s < 4; ++s) {
      int slot = sbase + s;
      float val;
      if (slot < 32) val = 0.5f + (float)slot * (99.5f/31.f);
      else {
        int idx = slot - 32, g = idx >> 3, sx = idx & 7;
        int lq = lr*4 + g;
        float mu = sMean[lq], sd = sStd[lq];
        val = fminf(fmaxf(mu + sd*noise[(size_t)(qbase + lq)*8 + sx], 0.5f), 100.f);
      }
      fbuf[lr*64 + slot] = val;
      vals[s] = val;
    }
    __syncthreads();
    int rk[4] = {0,0,0,0};
    for (int k = 0; k < 64; ++k) {
      float o = fbuf[lr*64 + k];
      #pragma unroll
      for (int s = 0; s < 4; ++s)
        rk[s] += (o < vals[s]) || (o == vals[s] && k < sbase + s);
    }
    int gray = (qbase >> 2) + lr;
    #pragma unroll
    for (int s = 0; s < 4; ++s)
      dsort[(size_t)gray*64 + rk[s]] = vals[s];
  }
}

extern "C" void kernel_launch(void* const* d_in, const int* in_sizes, int n_in,
                              void* d_out, int out_size, void* d_ws, size_t ws_size,
                              hipStream_t stream)
{
  const float* bev   = (const float*)d_in[0];
  const float* camK  = (const float*)d_in[1];
  const float* img_s = (const float*)d_in[2];
  const float* img_t = (const float*)d_in[3];
  const float* Tsi   = (const float*)d_in[4];
  const float* Tst   = (const float*)d_in[5];
  const float* noise = (const float*)d_in[6];
  const int*   pix   = (const int*)d_in[7];
  const float* m_w_in=(const float*)d_in[8];  const float* m_b_in=(const float*)d_in[9];
  const float* m_wz  =(const float*)d_in[10]; const float* m_bz  =(const float*)d_in[11];
  const float* m_w0  =(const float*)d_in[12]; const float* m_b0  =(const float*)d_in[13];
  const float* m_w1  =(const float*)d_in[14]; const float* m_b1  =(const float*)d_in[15];
  const float* m_wo  =(const float*)d_in[16]; const float* m_bo  =(const float*)d_in[17];
  const float* g_w_in=(const float*)d_in[18]; const float* g_b_in=(const float*)d_in[19];
  const float* g_wz  =(const float*)d_in[20]; const float* g_bz  =(const float*)d_in[21];
  const float* g_w0  =(const float*)d_in[22]; const float* g_b0  =(const float*)d_in[23];
  const float* g_w1  =(const float*)d_in[24]; const float* g_b1  =(const float*)d_in[25];
  const float* g_wo  =(const float*)d_in[26]; const float* g_bo  =(const float*)d_in[27];

  int R = in_sizes[7] / 2;
  float* ws = (float*)d_ws;
  size_t off = 0;
  float* unitb = ws + off; off += (size_t)R*3;
  float* vdirb = ws + off; off += (size_t)R*3;
  float* means = ws + off; off += (size_t)R*4;
  float* stds  = ws + off; off += (size_t)R*4;
  float* dsort = ws + off; off += (size_t)R*64;
  float* outbf = ws + off; off += (size_t)R*256;   // (kept in layout; no longer used)
  ushort_t* pkM = (ushort_t*)(ws + off);
  ushort_t* pkG = pkM + 39*4096;
  off += 39*4096 + 64;
  off = (off + 63) & ~(size_t)63;
  ushort_t* vfh = (ushort_t*)(ws + off);
  size_t need = off*4ull + (size_t)16*128*128*128*2ull;
  int mode = (ws_size >= need) ? 1 : 0;
  (void)outbf;

  k_prep<<<9440,256,0,stream>>>(bev, vfh, mode,
      m_w_in,m_wz,m_w0,m_w1,m_wo, g_w_in,g_wz,g_w0,g_w1,g_wo,
      pkM, pkG, (float*)d_out);
  k_fused<2><<<R/32,512,0,stream>>>(vfh,bev,mode,camK,pix,noise,unitb,vdirb,Tsi,dsort,pkG,
      g_b_in,g_bz,g_b0,g_b1,g_bo, means,stds,nullptr, nullptr,nullptr,nullptr);
  k_fused<4><<<R/2,512,0,stream>>>(vfh,bev,mode,camK,pix,noise,unitb,vdirb,Tsi,dsort,pkM,
      m_b_in,m_bz,m_b0,m_b1,m_bo, means,stds,(float*)d_out, img_s,img_t,Tst);
}